// Round 1
// baseline (1038.475 us; speedup 1.0000x reference)
//
#include <hip/hip_runtime.h>
#include <hip/hip_bf16.h>

// FSNet: embed -> bi-GRU(2) encoder -> broadcast -> bi-GRU(2) decoder
//        -> fc head (64x20) + reconstruction GEMM (64x100x10000)
// External dtypes: float32 (per reference); x int32. Outputs float32.
// Internal: bf16 only as MFMA operands.

typedef __bf16 bf16x8 __attribute__((ext_vector_type(8)));
typedef float f32x4 __attribute__((ext_vector_type(4)));

__device__ __forceinline__ ushort f2bf(float f) {
    __hip_bfloat16 h = __float2bfloat16(f);   // RNE
    return *reinterpret_cast<ushort*>(&h);
}
__device__ __forceinline__ float sigm(float x) {          // x finite, |x| small -> no overflow path to NaN
    return 1.f / (1.f + __expf(-x));
}
__device__ __forceinline__ float tanh_f(float x) {
    x = fminf(fmaxf(x, -15.f), 15.f);                     // keeps exp finite; sanitizes NaN
    float e = __expf(2.f * x);
    return (e - 1.f) / (e + 1.f);
}

// ---------------------------------------------------------------- embedding: fp32 emb -> bf16
__global__ __launch_bounds__(256) void emb_gather(const int* __restrict__ x,
                                                  const float* __restrict__ emb,
                                                  ushort* __restrict__ e) {
    int idx = blockIdx.x * 256 + threadIdx.x;     // < 6400*16
    int row = idx >> 4, k8 = idx & 15;
    int xi = x[row];
    xi = xi > 9999 ? 9999 : (xi < 0 ? 0 : xi);
    const float* src = &emb[(size_t)xi * 128 + k8 * 8];
    ushort4 lo, hi;
    lo.x = f2bf(src[0]); lo.y = f2bf(src[1]); lo.z = f2bf(src[2]); lo.w = f2bf(src[3]);
    hi.x = f2bf(src[4]); hi.y = f2bf(src[5]); hi.z = f2bf(src[6]); hi.w = f2bf(src[7]);
    ushort* dst = &e[row * 128 + k8 * 8];
    *reinterpret_cast<ushort4*>(dst)     = lo;
    *reinterpret_cast<ushort4*>(dst + 4) = hi;
}

// ---------------------------------------------------------------- fp32 -> bf16 bulk convert (8/thread)
__global__ __launch_bounds__(256) void cvt_f32_bf16(const float* __restrict__ src,
                                                    ushort* __restrict__ dst, int n8) {
    int i = blockIdx.x * 256 + threadIdx.x;
    if (i >= n8) return;
    const float* s = src + (size_t)i * 8;
    ushort4 lo, hi;
    lo.x = f2bf(s[0]); lo.y = f2bf(s[1]); lo.z = f2bf(s[2]); lo.w = f2bf(s[3]);
    hi.x = f2bf(s[4]); hi.y = f2bf(s[5]); hi.z = f2bf(s[6]); hi.w = f2bf(s[7]);
    ushort* d = dst + (size_t)i * 8;
    *reinterpret_cast<ushort4*>(d)     = lo;
    *reinterpret_cast<ushort4*>(d + 4) = hi;
}

// ---------------------------------------------------------------- GEMM C = A @ W.T + bias (fp32 out)
// A: [M][K] bf16. W: [N][K] fp32 or bf16 (template). 128x128 tile, 4 waves, mfma 16x16x32 bf16.
// bhh_fold (optional, N=768 GRU case): adds bhh[n] for gate cols (n%384)<256 (r,z biases).
template <bool WBF16>
__global__ __launch_bounds__(256) void gemm_bt(const ushort* __restrict__ A, int lda,
                                               const void* __restrict__ Wp, int ldw,
                                               const float* __restrict__ bias,
                                               const float* __restrict__ bhh_fold,
                                               float* __restrict__ C, int ldc,
                                               int M, int N, int K) {
    __shared__ __align__(16) ushort As[128 * 72];   // stride 72: rows 16B-aligned
    __shared__ __align__(16) ushort Ws[128 * 72];
    const int tid = threadIdx.x;
    const int lane = tid & 63, wave = tid >> 6;
    const int n0 = blockIdx.x * 128, m0 = blockIdx.y * 128;
    const int wm = (wave >> 1) * 64, wn = (wave & 1) * 64;
    const int lm = lane & 15, kq = lane >> 4;
    f32x4 acc[4][4] = {};

    for (int kb = 0; kb < K; kb += 64) {
        #pragma unroll
        for (int it = 0; it < 4; ++it) {            // A: 1024 chunks of 16B
            int chunk = it * 256 + tid;
            int row = chunk >> 3, kc = chunk & 7;
            int gm = m0 + row; gm = gm < M ? gm : M - 1;   // clamp: garbage rows never stored
            *reinterpret_cast<int4*>(&As[row * 72 + kc * 8]) =
                *reinterpret_cast<const int4*>(&A[(size_t)gm * lda + kb + kc * 8]);
        }
        if (WBF16) {
            const ushort* W = (const ushort*)Wp;
            #pragma unroll
            for (int it = 0; it < 4; ++it) {
                int chunk = it * 256 + tid;
                int row = chunk >> 3, kc = chunk & 7;
                int gn = n0 + row; gn = gn < N ? gn : N - 1;
                *reinterpret_cast<int4*>(&Ws[row * 72 + kc * 8]) =
                    *reinterpret_cast<const int4*>(&W[(size_t)gn * ldw + kb + kc * 8]);
            }
        } else {
            const float* W = (const float*)Wp;
            #pragma unroll
            for (int it = 0; it < 8; ++it) {        // W fp32: 2048 float4 chunks, cvt to bf16
                int chunk = it * 256 + tid;
                int row = chunk >> 4, kc = chunk & 15;
                int gn = n0 + row; gn = gn < N ? gn : N - 1;
                float4 w4 = *reinterpret_cast<const float4*>(&W[(size_t)gn * ldw + kb + kc * 4]);
                ushort4 b4;
                b4.x = f2bf(w4.x); b4.y = f2bf(w4.y); b4.z = f2bf(w4.z); b4.w = f2bf(w4.w);
                *reinterpret_cast<ushort4*>(&Ws[row * 72 + kc * 4]) = b4;
            }
        }
        __syncthreads();
        #pragma unroll
        for (int k2 = 0; k2 < 2; ++k2) {
            bf16x8 af[4], wf[4];
            #pragma unroll
            for (int tt = 0; tt < 4; ++tt) {
                af[tt] = *reinterpret_cast<const bf16x8*>(&As[(wm + tt * 16 + lm) * 72 + k2 * 32 + kq * 8]);
                wf[tt] = *reinterpret_cast<const bf16x8*>(&Ws[(wn + tt * 16 + lm) * 72 + k2 * 32 + kq * 8]);
            }
            #pragma unroll
            for (int tm = 0; tm < 4; ++tm)
                #pragma unroll
                for (int tn = 0; tn < 4; ++tn)
                    acc[tm][tn] = __builtin_amdgcn_mfma_f32_16x16x32_bf16(af[tm], wf[tn], acc[tm][tn], 0, 0, 0);
        }
        __syncthreads();
    }
    float bn[4];
    #pragma unroll
    for (int tn = 0; tn < 4; ++tn) {
        int n = n0 + wn + tn * 16 + lm;
        float b = 0.f;
        if (n < N) {
            if (bias) b = bias[n];
            if (bhh_fold) {                         // fold bhh for r,z gate columns
                int c = n < 384 ? n : n - 384;
                if (c < 256) b += bhh_fold[n];
            }
        }
        bn[tn] = b;
    }
    #pragma unroll
    for (int tm = 0; tm < 4; ++tm) {
        int mbase = m0 + wm + tm * 16 + kq * 4;   // C/D: col=lane&15, row=quad*4+reg (m89-verified)
        #pragma unroll
        for (int tn = 0; tn < 4; ++tn) {
            int n = n0 + wn + tn * 16 + lm;
            if (n < N) {
                #pragma unroll
                for (int i = 0; i < 4; ++i) {
                    int m = mbase + i;
                    if (m < M) C[(size_t)m * ldc + n] = acc[tm][tn][i] + bn[tn];
                }
            }
        }
    }
}

// ---------------------------------------------------------------- GRU scan (in-register gates)
// 8 blocks = dir*4 + batch_quarter (16 rows). 512 thr = 8 waves.
// Wave w computes n-tiles {w, 8+w, 16+w} => lane (kq,lm) holds ghr/ghz/ghn for
// j = w*16+lm, batch rows kq*4+0..3 IN ACC REGISTERS after MFMA (C/D: col=lane&15,
// row=quad*4+reg). Nonlinearity fully in-register; only h round-trips LDS
// (double-buffered -> ONE barrier/step). gi(t+1) register-prefetched each step.
// bhh r,z biases pre-folded into gi by the GEMM epilogue; only bhn needed here.
__global__ __launch_bounds__(512) void gru_scan(const float* __restrict__ gi, int gi_tconst,
                                                const float* __restrict__ Whh,   // [2][384][128] fp32
                                                const float* __restrict__ bhh,   // [2][384] fp32
                                                ushort* __restrict__ y,          // [64][100][256] bf16 or null
                                                float* __restrict__ hf32,        // [64][512]
                                                ushort* __restrict__ hbf,        // [64][512] bf16 or null
                                                int hoff) {
    __shared__ __align__(16) ushort hbuf[2][16 * 136];   // bf16 h, [b][k] stride 136, double-buffered
    const int d = blockIdx.x >> 2, q = blockIdx.x & 3;
    const int tid = threadIdx.x;
    const int lane = tid & 63, w = tid >> 6;
    const int lm = lane & 15, kq = lane >> 4;
    const int j = w * 16 + lm;                            // this lane's hidden index

    for (int i = tid; i < 16 * 136; i += 512) hbuf[0][i] = 0;

    // B-frags for n-tiles {w, 8+w, 16+w}: lane's col = g*128 + j, k = kb*32 + kq*8 + idx.
    bf16x8 bfr[3][4];
    {
        const float* Wd = Whh + (size_t)d * 384 * 128;
        #pragma unroll
        for (int g = 0; g < 3; ++g)
            #pragma unroll
            for (int kb = 0; kb < 4; ++kb) {
                const float* p = &Wd[(size_t)(g * 128 + j) * 128 + kb * 32 + kq * 8];
                union { ushort u[8]; bf16x8 v; } t;
                #pragma unroll
                for (int e2 = 0; e2 < 8; ++e2) t.u[e2] = f2bf(p[e2]);
                bfr[g][kb] = t.v;
            }
    }
    const float bhn = bhh[d * 384 + 256 + j];
    const bool rev = (d == 1);

    float hreg[4] = {0.f, 0.f, 0.f, 0.f};
    float gr[4], gz[4], gn[4];
    {   // initial gi load (t = first step)
        int t0 = rev ? 99 : 0;
        #pragma unroll
        for (int r = 0; r < 4; ++r) {
            int b = q * 16 + kq * 4 + r;
            const float* g = gi_tconst ? gi + (size_t)b * 768 + d * 384
                                       : gi + ((size_t)b * 100 + t0) * 768 + d * 384;
            gr[r] = g[j]; gz[r] = g[128 + j]; gn[r] = g[256 + j];
        }
    }
    __syncthreads();

    for (int ti = 0; ti < 100; ++ti) {
        int t = rev ? 99 - ti : ti;
        // prefetch gi(t+1): in flight across the whole step's compute
        float pr[4], pz[4], pn[4];
        if (!gi_tconst && ti < 99) {
            int tn2 = rev ? 99 - (ti + 1) : ti + 1;
            #pragma unroll
            for (int r = 0; r < 4; ++r) {
                int b = q * 16 + kq * 4 + r;
                const float* g = gi + ((size_t)b * 100 + tn2) * 768 + d * 384;
                pr[r] = g[j]; pz[r] = g[128 + j]; pn[r] = g[256 + j];
            }
        }
        // A-frags: A[m=lm][k] from current h buffer
        const ushort* hb = hbuf[ti & 1];
        bf16x8 afr[4];
        #pragma unroll
        for (int kb = 0; kb < 4; ++kb)
            afr[kb] = *reinterpret_cast<const bf16x8*>(&hb[lm * 136 + kb * 32 + kq * 8]);
        // gh = h @ Whh.T : three acc chains (r,z,n) land in this lane's registers
        f32x4 aR = {0,0,0,0}, aZ = {0,0,0,0}, aN = {0,0,0,0};
        #pragma unroll
        for (int kb = 0; kb < 4; ++kb) {
            aR = __builtin_amdgcn_mfma_f32_16x16x32_bf16(afr[kb], bfr[0][kb], aR, 0, 0, 0);
            aZ = __builtin_amdgcn_mfma_f32_16x16x32_bf16(afr[kb], bfr[1][kb], aZ, 0, 0, 0);
            aN = __builtin_amdgcn_mfma_f32_16x16x32_bf16(afr[kb], bfr[2][kb], aN, 0, 0, 0);
        }
        // nonlinearity, fully in-register (gi already has bih + bhh_{r,z} folded)
        ushort* hw = hbuf[(ti + 1) & 1];
        #pragma unroll
        for (int r = 0; r < 4; ++r) {
            float rr = sigm(gr[r] + aR[r]);
            float zz = sigm(gz[r] + aZ[r]);
            float nn = tanh_f(gn[r] + rr * (aN[r] + bhn));
            float h = nn + zz * (hreg[r] - nn);
            hreg[r] = h;
            hw[(kq * 4 + r) * 136 + j] = f2bf(h);
            if (y) {
                int b = q * 16 + kq * 4 + r;
                y[((size_t)b * 100 + t) * 256 + d * 128 + j] = f2bf(h);
            }
        }
        if (!gi_tconst && ti < 99) {
            #pragma unroll
            for (int r = 0; r < 4; ++r) { gr[r] = pr[r]; gz[r] = pz[r]; gn[r] = pn[r]; }
        }
        __syncthreads();
    }
    #pragma unroll
    for (int r = 0; r < 4; ++r) {
        int b = q * 16 + kq * 4 + r;
        int col = hoff + d * 128 + j;   // torch hidden layout: [l0f,l0b,l1f,l1b]
        hf32[(size_t)b * 512 + col] = hreg[r];
        if (hbf) hbf[(size_t)b * 512 + col] = f2bf(hreg[r]);
    }
}

// ---------------------------------------------------------------- fc head: out = [enc_h, dec_h] @ fc_W.T + fc_b
__global__ __launch_bounds__(256) void fc_out(const float* __restrict__ ench,
                                              const float* __restrict__ dech,
                                              const float* __restrict__ W,
                                              const float* __restrict__ bias,
                                              float* __restrict__ out) {
    __shared__ float v[1024];
    int b = blockIdx.x, tid = threadIdx.x;
    for (int i = tid; i < 1024; i += 256)
        v[i] = (i < 512) ? ench[b * 512 + i] : dech[b * 512 + i - 512];
    __syncthreads();
    int wave = tid >> 6, lane = tid & 63;
    for (int c = wave; c < 20; c += 4) {
        float s = 0.f;
        for (int k = lane; k < 1024; k += 64) s += v[k] * W[c * 1024 + k];
        #pragma unroll
        for (int off = 32; off >= 1; off >>= 1) s += __shfl_xor(s, off, 64);
        if (lane == 0) out[b * 20 + c] = s + bias[c];
    }
}

// ---------------------------------------------------------------- launch
extern "C" void kernel_launch(void* const* d_in, const int* in_sizes, int n_in,
                              void* d_out, int out_size, void* d_ws, size_t ws_size,
                              hipStream_t stream) {
    const int*   x     = (const int*)  d_in[0];
    const float* emb   = (const float*)d_in[1];
    const float* eWih0 = (const float*)d_in[2];
    const float* eWhh0 = (const float*)d_in[3];
    const float* ebih0 = (const float*)d_in[4];
    const float* ebhh0 = (const float*)d_in[5];
    const float* eWih1 = (const float*)d_in[6];
    const float* eWhh1 = (const float*)d_in[7];
    const float* ebih1 = (const float*)d_in[8];
    const float* ebhh1 = (const float*)d_in[9];
    const float* dWih0 = (const float*)d_in[10];
    const float* dWhh0 = (const float*)d_in[11];
    const float* dbih0 = (const float*)d_in[12];
    const float* dbhh0 = (const float*)d_in[13];
    const float* dWih1 = (const float*)d_in[14];
    const float* dWhh1 = (const float*)d_in[15];
    const float* dbih1 = (const float*)d_in[16];
    const float* dbhh1 = (const float*)d_in[17];
    const float* fcW   = (const float*)d_in[18];
    const float* fcb   = (const float*)d_in[19];
    const float* recW  = (const float*)d_in[20];
    const float* recb  = (const float*)d_in[21];

    char* ws = (char*)d_ws;
    size_t off = 0;
    auto alloc = [&](size_t bytes) {
        char* p = ws + off;
        off = (off + bytes + 255) & ~(size_t)255;
        return p;
    };
    float*  gi    = (float*) alloc((size_t)6400 * 768 * 4);   // gate inputs (fp32, reused 3x)
    ushort* yA    = (ushort*)alloc((size_t)6400 * 256 * 2);   // enc l0 / dec l0 output seq (bf16)
    ushort* y1d   = (ushort*)alloc((size_t)6400 * 256 * 2);   // dec l1 output = rec_seq (bf16)
    ushort* e_buf = (ushort*)alloc((size_t)6400 * 128 * 2);   // embeddings (bf16)
    float*  digi  = (float*) alloc((size_t)64 * 768 * 4);     // dec l0 time-constant gi
    float*  enchf = (float*) alloc((size_t)64 * 512 * 4);
    ushort* enchb = (ushort*)alloc((size_t)64 * 512 * 2);
    float*  dechf = (float*) alloc((size_t)64 * 512 * 4);
    size_t ws_used = off;
    ushort* recWb = (ushort*)gi;   // bf16 recW aliased over gi (gi dead after last scan; 5.12MB <= 19.6MB)

    float* out_fc  = (float*)d_out;              // [64][20]
    float* out_rec = (float*)d_out + 1280;       // [64][100][10000]

    hipMemsetAsync(d_ws, 0, ws_used, stream);

    emb_gather<<<6400 * 16 / 256, 256, 0, stream>>>(x, emb, e_buf);
    // encoder layer 0 (bhh r,z folded into gi)
    gemm_bt<false><<<dim3(6, 50), 256, 0, stream>>>(e_buf, 128, eWih0, 128, ebih0, ebhh0, gi, 768, 6400, 768, 128);
    gru_scan<<<8, 512, 0, stream>>>(gi, 0, eWhh0, ebhh0, yA, enchf, enchb, 0);
    // encoder layer 1 (only final h needed)
    gemm_bt<false><<<dim3(6, 50), 256, 0, stream>>>(yA, 256, eWih1, 256, ebih1, ebhh1, gi, 768, 6400, 768, 256);
    gru_scan<<<8, 512, 0, stream>>>(gi, 0, eWhh1, ebhh1, nullptr, enchf, enchb, 256);
    // decoder layer 0: broadcast enc_h -> gi constant over t
    gemm_bt<false><<<dim3(6, 1), 256, 0, stream>>>(enchb, 512, dWih0, 512, dbih0, dbhh0, digi, 768, 64, 768, 512);
    gru_scan<<<8, 512, 0, stream>>>(digi, 1, dWhh0, dbhh0, yA, dechf, nullptr, 0);
    // decoder layer 1
    gemm_bt<false><<<dim3(6, 50), 256, 0, stream>>>(yA, 256, dWih1, 256, dbih1, dbhh1, gi, 768, 6400, 768, 256);
    gru_scan<<<8, 512, 0, stream>>>(gi, 0, dWhh1, dbhh1, y1d, dechf, nullptr, 256);
    // reconstruction GEMM: pre-convert recW to bf16 (halves the 50x-reread W stream), then GEMM
    cvt_f32_bf16<<<(10000 * 256 / 8 + 255) / 256, 256, 0, stream>>>(recW, recWb, 10000 * 256 / 8);
    gemm_bt<true><<<dim3(79, 50), 256, 0, stream>>>(y1d, 256, recWb, 256, recb, nullptr, out_rec, 10000, 6400, 10000, 256);
    // fc head
    fc_out<<<64, 256, 0, stream>>>(enchf, dechf, fcW, fcb, out_fc);
}

// Round 2
// 1028.393 us; speedup vs baseline: 1.0098x; 1.0098x over previous
//
#include <hip/hip_runtime.h>
#include <hip/hip_bf16.h>

// FSNet: embed -> bi-GRU(2) encoder -> broadcast -> bi-GRU(2) decoder
//        -> fc head (64x20) + reconstruction GEMM (64x100x10000)
// R1 changes vs R0 baseline (1038.5 us):
//  - gru_scan: __syncthreads -> lgkmcnt(0)+s_barrier (y-stores / gi-loads stay in flight)
//  - all W (4x Wih + recW) pre-converted to bf16 in ONE cvt_all dispatch; GEMM W path always bf16
//  - emb_gather fused into gemm0 A-staging (AGATHER template path)
//  - workspace memset dropped (all buffers write-before-read)
// Numerics identical to R0 (same f2bf RNE conversions, same MFMA order).

typedef __bf16 bf16x8 __attribute__((ext_vector_type(8)));
typedef float f32x4 __attribute__((ext_vector_type(4)));

__device__ __forceinline__ ushort f2bf(float f) {
    __hip_bfloat16 h = __float2bfloat16(f);   // RNE
    return *reinterpret_cast<ushort*>(&h);
}
__device__ __forceinline__ float sigm(float x) {
    return 1.f / (1.f + __expf(-x));
}
__device__ __forceinline__ float tanh_f(float x) {
    x = fminf(fmaxf(x, -15.f), 15.f);
    float e = __expf(2.f * x);
    return (e - 1.f) / (e + 1.f);
}
// LDS-only barrier: orders ds_write -> ds_read without draining vmcnt (global
// stores/loads stay in flight across it). "memory" clobber pins memory ops.
__device__ __forceinline__ void lds_barrier() {
    asm volatile("s_waitcnt lgkmcnt(0)" ::: "memory");
    __builtin_amdgcn_s_barrier();
}

// ---------------------------------------------------------------- fp32 -> bf16, 5 segments, one dispatch
// dst layout (elements): [eWih0:98304][eWih1:196608][dWih0:393216][dWih1:196608][recW:2560000]
__global__ __launch_bounds__(256) void cvt_all(const float* __restrict__ s0,
                                               const float* __restrict__ s1,
                                               const float* __restrict__ s2,
                                               const float* __restrict__ s3,
                                               const float* __restrict__ s4,
                                               ushort* __restrict__ dst) {
    int i = blockIdx.x * 256 + threadIdx.x;         // 430592 threads exactly
    size_t e = (size_t)i * 8;
    const float* s; size_t off;
    if      (e < 98304)  { s = s0; off = e; }
    else if (e < 294912) { s = s1; off = e - 98304; }
    else if (e < 688128) { s = s2; off = e - 294912; }
    else if (e < 884736) { s = s3; off = e - 688128; }
    else                 { s = s4; off = e - 884736; }
    const float* p = s + off;
    ushort4 lo, hi;
    lo.x = f2bf(p[0]); lo.y = f2bf(p[1]); lo.z = f2bf(p[2]); lo.w = f2bf(p[3]);
    hi.x = f2bf(p[4]); hi.y = f2bf(p[5]); hi.z = f2bf(p[6]); hi.w = f2bf(p[7]);
    ushort* d = dst + e;
    *reinterpret_cast<ushort4*>(d)     = lo;
    *reinterpret_cast<ushort4*>(d + 4) = hi;
}

// ---------------------------------------------------------------- GEMM C = A @ W.T + bias (fp32 out)
// A: [M][K] bf16 (or AGATHER: emb rows via x, fp32->bf16 in staging). W: [N][K] bf16.
// 128x128 tile, 4 waves, mfma 16x16x32 bf16.
// bhh_fold (optional, N=768 GRU case): adds bhh[n] for gate cols (n%384)<256 (r,z biases).
template <bool AGATHER>
__global__ __launch_bounds__(256) void gemm_bt(const ushort* __restrict__ A, int lda,
                                               const ushort* __restrict__ W, int ldw,
                                               const float* __restrict__ bias,
                                               const float* __restrict__ bhh_fold,
                                               float* __restrict__ C, int ldc,
                                               int M, int N, int K,
                                               const float* __restrict__ embp,
                                               const int* __restrict__ xidx) {
    __shared__ __align__(16) ushort As[128 * 72];   // stride 72: rows 16B-aligned, conflict-free
    __shared__ __align__(16) ushort Ws[128 * 72];
    const int tid = threadIdx.x;
    const int lane = tid & 63, wave = tid >> 6;
    const int n0 = blockIdx.x * 128, m0 = blockIdx.y * 128;
    const int wm = (wave >> 1) * 64, wn = (wave & 1) * 64;
    const int lm = lane & 15, kq = lane >> 4;
    f32x4 acc[4][4] = {};

    for (int kb = 0; kb < K; kb += 64) {
        if (AGATHER) {
            // A rows gathered from emb via x (fp32 -> bf16). K=128 here.
            #pragma unroll
            for (int it = 0; it < 8; ++it) {        // 2048 float4 chunks
                int chunk = it * 256 + tid;
                int row = chunk >> 4, kc = chunk & 15;
                int gm = m0 + row; gm = gm < M ? gm : M - 1;
                int xi = xidx[gm];
                xi = xi > 9999 ? 9999 : (xi < 0 ? 0 : xi);
                float4 a4 = *reinterpret_cast<const float4*>(&embp[(size_t)xi * 128 + kb + kc * 4]);
                ushort4 b4;
                b4.x = f2bf(a4.x); b4.y = f2bf(a4.y); b4.z = f2bf(a4.z); b4.w = f2bf(a4.w);
                *reinterpret_cast<ushort4*>(&As[row * 72 + kc * 4]) = b4;
            }
        } else {
            #pragma unroll
            for (int it = 0; it < 4; ++it) {        // A: 1024 chunks of 16B
                int chunk = it * 256 + tid;
                int row = chunk >> 3, kc = chunk & 7;
                int gm = m0 + row; gm = gm < M ? gm : M - 1;   // clamp: garbage rows never stored
                *reinterpret_cast<int4*>(&As[row * 72 + kc * 8]) =
                    *reinterpret_cast<const int4*>(&A[(size_t)gm * lda + kb + kc * 8]);
            }
        }
        #pragma unroll
        for (int it = 0; it < 4; ++it) {            // W bf16: 1024 chunks of 16B
            int chunk = it * 256 + tid;
            int row = chunk >> 3, kc = chunk & 7;
            int gn = n0 + row; gn = gn < N ? gn : N - 1;
            *reinterpret_cast<int4*>(&Ws[row * 72 + kc * 8]) =
                *reinterpret_cast<const int4*>(&W[(size_t)gn * ldw + kb + kc * 8]);
        }
        __syncthreads();
        #pragma unroll
        for (int k2 = 0; k2 < 2; ++k2) {
            bf16x8 af[4], wf[4];
            #pragma unroll
            for (int tt = 0; tt < 4; ++tt) {
                af[tt] = *reinterpret_cast<const bf16x8*>(&As[(wm + tt * 16 + lm) * 72 + k2 * 32 + kq * 8]);
                wf[tt] = *reinterpret_cast<const bf16x8*>(&Ws[(wn + tt * 16 + lm) * 72 + k2 * 32 + kq * 8]);
            }
            #pragma unroll
            for (int tm = 0; tm < 4; ++tm)
                #pragma unroll
                for (int tn = 0; tn < 4; ++tn)
                    acc[tm][tn] = __builtin_amdgcn_mfma_f32_16x16x32_bf16(af[tm], wf[tn], acc[tm][tn], 0, 0, 0);
        }
        __syncthreads();
    }
    float bn[4];
    #pragma unroll
    for (int tn = 0; tn < 4; ++tn) {
        int n = n0 + wn + tn * 16 + lm;
        float b = 0.f;
        if (n < N) {
            if (bias) b = bias[n];
            if (bhh_fold) {                         // fold bhh for r,z gate columns
                int c = n < 384 ? n : n - 384;
                if (c < 256) b += bhh_fold[n];
            }
        }
        bn[tn] = b;
    }
    #pragma unroll
    for (int tm = 0; tm < 4; ++tm) {
        int mbase = m0 + wm + tm * 16 + kq * 4;   // C/D: col=lane&15, row=quad*4+reg (m89-verified)
        #pragma unroll
        for (int tn = 0; tn < 4; ++tn) {
            int n = n0 + wn + tn * 16 + lm;
            if (n < N) {
                #pragma unroll
                for (int i = 0; i < 4; ++i) {
                    int m = mbase + i;
                    if (m < M) C[(size_t)m * ldc + n] = acc[tm][tn][i] + bn[tn];
                }
            }
        }
    }
}

// ---------------------------------------------------------------- GRU scan (in-register gates)
// 8 blocks = dir*4 + batch_quarter (16 rows). 512 thr = 8 waves.
// Wave w computes n-tiles {w, 8+w, 16+w} => lane (kq,lm) holds ghr/ghz/ghn for
// j = w*16+lm, batch rows kq*4+0..3 IN ACC REGISTERS after MFMA. Nonlinearity
// fully in-register; only h round-trips LDS (double-buffered -> ONE lds_barrier/step;
// y global stores and gi prefetch loads stay in flight across it).
// bhh r,z biases pre-folded into gi by the GEMM epilogue; only bhn needed here.
__global__ __launch_bounds__(512) void gru_scan(const float* __restrict__ gi, int gi_tconst,
                                                const float* __restrict__ Whh,   // [2][384][128] fp32
                                                const float* __restrict__ bhh,   // [2][384] fp32
                                                ushort* __restrict__ y,          // [64][100][256] bf16 or null
                                                float* __restrict__ hf32,        // [64][512]
                                                ushort* __restrict__ hbf,        // [64][512] bf16 or null
                                                int hoff) {
    __shared__ __align__(16) ushort hbuf[2][16 * 136];   // bf16 h, [b][k] stride 136, double-buffered
    const int d = blockIdx.x >> 2, q = blockIdx.x & 3;
    const int tid = threadIdx.x;
    const int lane = tid & 63, w = tid >> 6;
    const int lm = lane & 15, kq = lane >> 4;
    const int j = w * 16 + lm;                            // this lane's hidden index

    for (int i = tid; i < 16 * 136; i += 512) hbuf[0][i] = 0;

    // B-frags for n-tiles {w, 8+w, 16+w}: lane's col = g*128 + j, k = kb*32 + kq*8 + idx.
    bf16x8 bfr[3][4];
    {
        const float* Wd = Whh + (size_t)d * 384 * 128;
        #pragma unroll
        for (int g = 0; g < 3; ++g)
            #pragma unroll
            for (int kb = 0; kb < 4; ++kb) {
                const float* p = &Wd[(size_t)(g * 128 + j) * 128 + kb * 32 + kq * 8];
                union { ushort u[8]; bf16x8 v; } t;
                #pragma unroll
                for (int e2 = 0; e2 < 8; ++e2) t.u[e2] = f2bf(p[e2]);
                bfr[g][kb] = t.v;
            }
    }
    const float bhn = bhh[d * 384 + 256 + j];
    const bool rev = (d == 1);

    float hreg[4] = {0.f, 0.f, 0.f, 0.f};
    float gr[4], gz[4], gn[4];
    {   // initial gi load (t = first step)
        int t0 = rev ? 99 : 0;
        #pragma unroll
        for (int r = 0; r < 4; ++r) {
            int b = q * 16 + kq * 4 + r;
            const float* g = gi_tconst ? gi + (size_t)b * 768 + d * 384
                                       : gi + ((size_t)b * 100 + t0) * 768 + d * 384;
            gr[r] = g[j]; gz[r] = g[128 + j]; gn[r] = g[256 + j];
        }
    }
    lds_barrier();

    for (int ti = 0; ti < 100; ++ti) {
        int t = rev ? 99 - ti : ti;
        // prefetch gi(t+1): in flight across the whole step's compute
        float pr[4], pz[4], pn[4];
        if (!gi_tconst && ti < 99) {
            int tn2 = rev ? 99 - (ti + 1) : ti + 1;
            #pragma unroll
            for (int r = 0; r < 4; ++r) {
                int b = q * 16 + kq * 4 + r;
                const float* g = gi + ((size_t)b * 100 + tn2) * 768 + d * 384;
                pr[r] = g[j]; pz[r] = g[128 + j]; pn[r] = g[256 + j];
            }
        }
        // A-frags: A[m=lm][k] from current h buffer
        const ushort* hb = hbuf[ti & 1];
        bf16x8 afr[4];
        #pragma unroll
        for (int kb = 0; kb < 4; ++kb)
            afr[kb] = *reinterpret_cast<const bf16x8*>(&hb[lm * 136 + kb * 32 + kq * 8]);
        // gh = h @ Whh.T : three acc chains (r,z,n) land in this lane's registers
        f32x4 aR = {0,0,0,0}, aZ = {0,0,0,0}, aN = {0,0,0,0};
        #pragma unroll
        for (int kb = 0; kb < 4; ++kb) {
            aR = __builtin_amdgcn_mfma_f32_16x16x32_bf16(afr[kb], bfr[0][kb], aR, 0, 0, 0);
            aZ = __builtin_amdgcn_mfma_f32_16x16x32_bf16(afr[kb], bfr[1][kb], aZ, 0, 0, 0);
            aN = __builtin_amdgcn_mfma_f32_16x16x32_bf16(afr[kb], bfr[2][kb], aN, 0, 0, 0);
        }
        // nonlinearity, fully in-register (gi already has bih + bhh_{r,z} folded)
        ushort* hw = hbuf[(ti + 1) & 1];
        #pragma unroll
        for (int r = 0; r < 4; ++r) {
            float rr = sigm(gr[r] + aR[r]);
            float zz = sigm(gz[r] + aZ[r]);
            float nn = tanh_f(gn[r] + rr * (aN[r] + bhn));
            float h = nn + zz * (hreg[r] - nn);
            hreg[r] = h;
            hw[(kq * 4 + r) * 136 + j] = f2bf(h);
            if (y) {
                int b = q * 16 + kq * 4 + r;
                y[((size_t)b * 100 + t) * 256 + d * 128 + j] = f2bf(h);
            }
        }
        if (!gi_tconst && ti < 99) {
            #pragma unroll
            for (int r = 0; r < 4; ++r) { gr[r] = pr[r]; gz[r] = pz[r]; gn[r] = pn[r]; }
        }
        lds_barrier();   // LDS-only: y stores stay in flight; kernel-end drain covers them
    }
    #pragma unroll
    for (int r = 0; r < 4; ++r) {
        int b = q * 16 + kq * 4 + r;
        int col = hoff + d * 128 + j;   // torch hidden layout: [l0f,l0b,l1f,l1b]
        hf32[(size_t)b * 512 + col] = hreg[r];
        if (hbf) hbf[(size_t)b * 512 + col] = f2bf(hreg[r]);
    }
}

// ---------------------------------------------------------------- fc head: out = [enc_h, dec_h] @ fc_W.T + fc_b
__global__ __launch_bounds__(256) void fc_out(const float* __restrict__ ench,
                                              const float* __restrict__ dech,
                                              const float* __restrict__ W,
                                              const float* __restrict__ bias,
                                              float* __restrict__ out) {
    __shared__ float v[1024];
    int b = blockIdx.x, tid = threadIdx.x;
    for (int i = tid; i < 1024; i += 256)
        v[i] = (i < 512) ? ench[b * 512 + i] : dech[b * 512 + i - 512];
    __syncthreads();
    int wave = tid >> 6, lane = tid & 63;
    for (int c = wave; c < 20; c += 4) {
        float s = 0.f;
        for (int k = lane; k < 1024; k += 64) s += v[k] * W[c * 1024 + k];
        #pragma unroll
        for (int off = 32; off >= 1; off >>= 1) s += __shfl_xor(s, off, 64);
        if (lane == 0) out[b * 20 + c] = s + bias[c];
    }
}

// ---------------------------------------------------------------- launch
extern "C" void kernel_launch(void* const* d_in, const int* in_sizes, int n_in,
                              void* d_out, int out_size, void* d_ws, size_t ws_size,
                              hipStream_t stream) {
    const int*   x     = (const int*)  d_in[0];
    const float* emb   = (const float*)d_in[1];
    const float* eWih0 = (const float*)d_in[2];
    const float* eWhh0 = (const float*)d_in[3];
    const float* ebih0 = (const float*)d_in[4];
    const float* ebhh0 = (const float*)d_in[5];
    const float* eWih1 = (const float*)d_in[6];
    const float* eWhh1 = (const float*)d_in[7];
    const float* ebih1 = (const float*)d_in[8];
    const float* ebhh1 = (const float*)d_in[9];
    const float* dWih0 = (const float*)d_in[10];
    const float* dWhh0 = (const float*)d_in[11];
    const float* dbih0 = (const float*)d_in[12];
    const float* dbhh0 = (const float*)d_in[13];
    const float* dWih1 = (const float*)d_in[14];
    const float* dWhh1 = (const float*)d_in[15];
    const float* dbih1 = (const float*)d_in[16];
    const float* dbhh1 = (const float*)d_in[17];
    const float* fcW   = (const float*)d_in[18];
    const float* fcb   = (const float*)d_in[19];
    const float* recW  = (const float*)d_in[20];
    const float* recb  = (const float*)d_in[21];

    char* ws = (char*)d_ws;
    size_t off = 0;
    auto alloc = [&](size_t bytes) {
        char* p = ws + off;
        off = (off + bytes + 255) & ~(size_t)255;
        return p;
    };
    float*  gi    = (float*) alloc((size_t)6400 * 768 * 4);   // gate inputs (fp32, reused 3x)
    ushort* yA    = (ushort*)alloc((size_t)6400 * 256 * 2);   // enc l0 / dec l0 output seq (bf16)
    ushort* y1d   = (ushort*)alloc((size_t)6400 * 256 * 2);   // dec l1 output = rec_seq (bf16)
    ushort* wbuf  = (ushort*)alloc((size_t)3444736 * 2);      // bf16: eWih0|eWih1|dWih0|dWih1|recW
    float*  digi  = (float*) alloc((size_t)64 * 768 * 4);     // dec l0 time-constant gi
    float*  enchf = (float*) alloc((size_t)64 * 512 * 4);
    ushort* enchb = (ushort*)alloc((size_t)64 * 512 * 2);
    float*  dechf = (float*) alloc((size_t)64 * 512 * 4);
    (void)ws_size;

    ushort* w_e0  = wbuf;
    ushort* w_e1  = wbuf + 98304;
    ushort* w_d0  = wbuf + 294912;
    ushort* w_d1  = wbuf + 688128;
    ushort* w_rec = wbuf + 884736;

    float* out_fc  = (float*)d_out;              // [64][20]
    float* out_rec = (float*)d_out + 1280;       // [64][100][10000]

    // one-shot weight conversion (all Wih + recW -> bf16), 430592 threads exactly
    cvt_all<<<1682, 256, 0, stream>>>(eWih0, eWih1, dWih0, dWih1, recW, wbuf);

    // encoder layer 0: A gathered from emb via x (bhh r,z folded into gi)
    gemm_bt<true><<<dim3(6, 50), 256, 0, stream>>>(nullptr, 128, w_e0, 128, ebih0, ebhh0,
                                                   gi, 768, 6400, 768, 128, emb, x);
    gru_scan<<<8, 512, 0, stream>>>(gi, 0, eWhh0, ebhh0, yA, enchf, enchb, 0);
    // encoder layer 1 (only final h needed)
    gemm_bt<false><<<dim3(6, 50), 256, 0, stream>>>(yA, 256, w_e1, 256, ebih1, ebhh1,
                                                    gi, 768, 6400, 768, 256, nullptr, nullptr);
    gru_scan<<<8, 512, 0, stream>>>(gi, 0, eWhh1, ebhh1, nullptr, enchf, enchb, 256);
    // decoder layer 0: broadcast enc_h -> gi constant over t
    gemm_bt<false><<<dim3(6, 1), 256, 0, stream>>>(enchb, 512, w_d0, 512, dbih0, dbhh0,
                                                   digi, 768, 64, 768, 512, nullptr, nullptr);
    gru_scan<<<8, 512, 0, stream>>>(digi, 1, dWhh0, dbhh0, yA, dechf, nullptr, 0);
    // decoder layer 1
    gemm_bt<false><<<dim3(6, 50), 256, 0, stream>>>(yA, 256, w_d1, 256, dbih1, dbhh1,
                                                    gi, 768, 6400, 768, 256, nullptr, nullptr);
    gru_scan<<<8, 512, 0, stream>>>(gi, 0, dWhh1, dbhh1, y1d, dechf, nullptr, 256);
    // reconstruction GEMM
    gemm_bt<false><<<dim3(79, 50), 256, 0, stream>>>(y1d, 256, w_rec, 256, recb, nullptr,
                                                     out_rec, 10000, 6400, 10000, 256, nullptr, nullptr);
    // fc head
    fc_out<<<64, 256, 0, stream>>>(enchf, dechf, fcW, fcb, out_fc);
}

// Round 3
// 1004.577 us; speedup vs baseline: 1.0337x; 1.0237x over previous
//
#include <hip/hip_runtime.h>
#include <hip/hip_bf16.h>

// FSNet: embed -> bi-GRU(2) encoder -> broadcast -> bi-GRU(2) decoder
//        -> fc head (64x20) + reconstruction GEMM (64x100x10000)
// R2 changes vs R1 (1028.4 us):
//  - gemm_bt: global_load_lds width-16 staging (m97/m193 lever, +35-67% on ladder)
//    with linear [128][64] LDS tile + (row&7)<<4 XOR swizzle applied BOTH sides
//    (pre-swizzled global source addr for the DMA, swizzled ds_read on fragments)
//    -> bank-floor b128 reads, no reg round-trip in staging.
//  - rec GEMM epilogue: nontemporal C stores (256MB write no longer evicts A/W panels).
// Numerics identical (same bf16 conversions, same MFMA order).

typedef __bf16 bf16x8 __attribute__((ext_vector_type(8)));
typedef float f32x4 __attribute__((ext_vector_type(4)));

__device__ __forceinline__ ushort f2bf(float f) {
    __hip_bfloat16 h = __float2bfloat16(f);   // RNE
    return *reinterpret_cast<ushort*>(&h);
}
__device__ __forceinline__ float sigm(float x) {
    return 1.f / (1.f + __expf(-x));
}
__device__ __forceinline__ float tanh_f(float x) {
    x = fminf(fmaxf(x, -15.f), 15.f);
    float e = __expf(2.f * x);
    return (e - 1.f) / (e + 1.f);
}
// LDS-only barrier: orders ds_write -> ds_read without draining vmcnt.
__device__ __forceinline__ void lds_barrier() {
    asm volatile("s_waitcnt lgkmcnt(0)" ::: "memory");
    __builtin_amdgcn_s_barrier();
}
// async global->LDS, 16B per lane; lds base is wave-uniform, HW adds lane*16.
__device__ __forceinline__ void gload16(const void* g, void* l) {
    __builtin_amdgcn_global_load_lds(
        (const __attribute__((address_space(1))) unsigned int*)g,
        (__attribute__((address_space(3))) unsigned int*)l, 16, 0, 0);
}

// ---------------------------------------------------------------- fp32 -> bf16, 5 segments, one dispatch
// dst layout (elements): [eWih0:98304][eWih1:196608][dWih0:393216][dWih1:196608][recW:2560000]
__global__ __launch_bounds__(256) void cvt_all(const float* __restrict__ s0,
                                               const float* __restrict__ s1,
                                               const float* __restrict__ s2,
                                               const float* __restrict__ s3,
                                               const float* __restrict__ s4,
                                               ushort* __restrict__ dst) {
    int i = blockIdx.x * 256 + threadIdx.x;         // 430592 threads exactly
    size_t e = (size_t)i * 8;
    const float* s; size_t off;
    if      (e < 98304)  { s = s0; off = e; }
    else if (e < 294912) { s = s1; off = e - 98304; }
    else if (e < 688128) { s = s2; off = e - 294912; }
    else if (e < 884736) { s = s3; off = e - 688128; }
    else                 { s = s4; off = e - 884736; }
    const float* p = s + off;
    ushort4 lo, hi;
    lo.x = f2bf(p[0]); lo.y = f2bf(p[1]); lo.z = f2bf(p[2]); lo.w = f2bf(p[3]);
    hi.x = f2bf(p[4]); hi.y = f2bf(p[5]); hi.z = f2bf(p[6]); hi.w = f2bf(p[7]);
    ushort* d = dst + e;
    *reinterpret_cast<ushort4*>(d)     = lo;
    *reinterpret_cast<ushort4*>(d + 4) = hi;
}

// ---------------------------------------------------------------- GEMM C = A @ W.T + bias (fp32 out)
// A: [M][K] bf16 (or AGATHER: emb rows via x, fp32->bf16 reg-staged). W: [N][K] bf16.
// 128x128 tile, 4 waves, mfma 16x16x32 bf16. LDS linear [128][64]u16 with
// byte ^= ((row&7)<<4) swizzle (write via pre-swizzled gload source; read swizzled).
// OOB tile rows (N=10000 tail, M=64 case) read garbage from within ws -- never stored.
// bhh_fold (optional, N=768 GRU case): adds bhh[n] for gate cols (n%384)<256 (r,z biases).
template <bool AGATHER, bool NTC>
__global__ __launch_bounds__(256) void gemm_bt(const ushort* __restrict__ A, int lda,
                                               const ushort* __restrict__ W, int ldw,
                                               const float* __restrict__ bias,
                                               const float* __restrict__ bhh_fold,
                                               float* __restrict__ C, int ldc,
                                               int M, int N, int K,
                                               const float* __restrict__ embp,
                                               const int* __restrict__ xidx) {
    __shared__ __align__(16) ushort As[128 * 64];   // linear, 16KB
    __shared__ __align__(16) ushort Ws[128 * 64];
    const int tid = threadIdx.x;
    const int lane = tid & 63, wave = tid >> 6;
    const int n0 = blockIdx.x * 128, m0 = blockIdx.y * 128;
    const int wm = (wave >> 1) * 64, wn = (wave & 1) * 64;
    const int lm = lane & 15, kq = lane >> 4;
    const int swz = (lm & 7) << 4;                  // read-side XOR (row&7 == lm&7)
    f32x4 acc[4][4] = {};

    for (int kb = 0; kb < K; kb += 64) {
        if (AGATHER) {
            // A rows gathered from emb via x (fp32 -> bf16), swizzled ds_write.
            #pragma unroll
            for (int it = 0; it < 8; ++it) {        // 2048 float4 chunks
                int chunk = it * 256 + tid;
                int row = chunk >> 4, kc = chunk & 15;
                int xi = xidx[m0 + row];
                xi = xi > 9999 ? 9999 : (xi < 0 ? 0 : xi);
                float4 a4 = *reinterpret_cast<const float4*>(&embp[(size_t)xi * 128 + kb + kc * 4]);
                ushort4 b4;
                b4.x = f2bf(a4.x); b4.y = f2bf(a4.y); b4.z = f2bf(a4.z); b4.w = f2bf(a4.w);
                int sb = (row * 128 + kc * 8) ^ ((row & 7) << 4);
                *reinterpret_cast<ushort4*>((char*)As + sb) = b4;
            }
        } else {
            #pragma unroll
            for (int seg = 0; seg < 4; ++seg) {     // 4KB per wave, 1KB per call
                int chunk = (wave * 4 + seg) * 64 + lane;   // 0..1023
                int L  = chunk * 16;                         // linear LDS byte
                int Ls = L ^ (((L >> 7) & 7) << 4);          // logical byte stored here
                int row = Ls >> 7, colb = Ls & 127;
                gload16(&A[(size_t)(m0 + row) * lda + kb + (colb >> 1)],
                        (char*)As + (wave * 4 + seg) * 1024);
            }
        }
        #pragma unroll
        for (int seg = 0; seg < 4; ++seg) {         // W bf16 via gload_lds
            int chunk = (wave * 4 + seg) * 64 + lane;
            int L  = chunk * 16;
            int Ls = L ^ (((L >> 7) & 7) << 4);
            int row = Ls >> 7, colb = Ls & 127;
            gload16(&W[(size_t)(n0 + row) * ldw + kb + (colb >> 1)],
                    (char*)Ws + (wave * 4 + seg) * 1024);
        }
        __syncthreads();                            // drains vmcnt (gload) + lgkmcnt
        #pragma unroll
        for (int k2 = 0; k2 < 2; ++k2) {
            bf16x8 af[4], wf[4];
            #pragma unroll
            for (int tt = 0; tt < 4; ++tt) {
                int Pa = (wm + tt * 16 + lm) * 128 + k2 * 64 + kq * 16;
                int Pw = (wn + tt * 16 + lm) * 128 + k2 * 64 + kq * 16;
                af[tt] = *reinterpret_cast<const bf16x8*>((const char*)As + (Pa ^ swz));
                wf[tt] = *reinterpret_cast<const bf16x8*>((const char*)Ws + (Pw ^ swz));
            }
            #pragma unroll
            for (int tm = 0; tm < 4; ++tm)
                #pragma unroll
                for (int tn = 0; tn < 4; ++tn)
                    acc[tm][tn] = __builtin_amdgcn_mfma_f32_16x16x32_bf16(af[tm], wf[tn], acc[tm][tn], 0, 0, 0);
        }
        __syncthreads();
    }
    float bn[4];
    #pragma unroll
    for (int tn = 0; tn < 4; ++tn) {
        int n = n0 + wn + tn * 16 + lm;
        float b = 0.f;
        if (n < N) {
            if (bias) b = bias[n];
            if (bhh_fold) {                         // fold bhh for r,z gate columns
                int c = n < 384 ? n : n - 384;
                if (c < 256) b += bhh_fold[n];
            }
        }
        bn[tn] = b;
    }
    #pragma unroll
    for (int tm = 0; tm < 4; ++tm) {
        int mbase = m0 + wm + tm * 16 + kq * 4;   // C/D: col=lane&15, row=quad*4+reg (m89-verified)
        #pragma unroll
        for (int tn = 0; tn < 4; ++tn) {
            int n = n0 + wn + tn * 16 + lm;
            if (n < N) {
                #pragma unroll
                for (int i = 0; i < 4; ++i) {
                    int m = mbase + i;
                    if (m < M) {
                        float v = acc[tm][tn][i] + bn[tn];
                        if (NTC) __builtin_nontemporal_store(v, &C[(size_t)m * ldc + n]);
                        else     C[(size_t)m * ldc + n] = v;
                    }
                }
            }
        }
    }
}

// ---------------------------------------------------------------- GRU scan (in-register gates)
// 8 blocks = dir*4 + batch_quarter (16 rows). 512 thr = 8 waves.
// Wave w computes n-tiles {w, 8+w, 16+w} => lane (kq,lm) holds ghr/ghz/ghn for
// j = w*16+lm, batch rows kq*4+0..3 IN ACC REGISTERS after MFMA. Nonlinearity
// fully in-register; only h round-trips LDS (double-buffered -> ONE lds_barrier/step;
// y global stores and gi prefetch loads stay in flight across it).
__global__ __launch_bounds__(512) void gru_scan(const float* __restrict__ gi, int gi_tconst,
                                                const float* __restrict__ Whh,   // [2][384][128] fp32
                                                const float* __restrict__ bhh,   // [2][384] fp32
                                                ushort* __restrict__ y,          // [64][100][256] bf16 or null
                                                float* __restrict__ hf32,        // [64][512]
                                                ushort* __restrict__ hbf,        // [64][512] bf16 or null
                                                int hoff) {
    __shared__ __align__(16) ushort hbuf[2][16 * 136];   // bf16 h, [b][k] stride 136, double-buffered
    const int d = blockIdx.x >> 2, q = blockIdx.x & 3;
    const int tid = threadIdx.x;
    const int lane = tid & 63, w = tid >> 6;
    const int lm = lane & 15, kq = lane >> 4;
    const int j = w * 16 + lm;                            // this lane's hidden index

    for (int i = tid; i < 16 * 136; i += 512) hbuf[0][i] = 0;

    // B-frags for n-tiles {w, 8+w, 16+w}: lane's col = g*128 + j, k = kb*32 + kq*8 + idx.
    bf16x8 bfr[3][4];
    {
        const float* Wd = Whh + (size_t)d * 384 * 128;
        #pragma unroll
        for (int g = 0; g < 3; ++g)
            #pragma unroll
            for (int kb = 0; kb < 4; ++kb) {
                const float* p = &Wd[(size_t)(g * 128 + j) * 128 + kb * 32 + kq * 8];
                union { ushort u[8]; bf16x8 v; } t;
                #pragma unroll
                for (int e2 = 0; e2 < 8; ++e2) t.u[e2] = f2bf(p[e2]);
                bfr[g][kb] = t.v;
            }
    }
    const float bhn = bhh[d * 384 + 256 + j];
    const bool rev = (d == 1);

    float hreg[4] = {0.f, 0.f, 0.f, 0.f};
    float gr[4], gz[4], gn[4];
    {   // initial gi load (t = first step)
        int t0 = rev ? 99 : 0;
        #pragma unroll
        for (int r = 0; r < 4; ++r) {
            int b = q * 16 + kq * 4 + r;
            const float* g = gi_tconst ? gi + (size_t)b * 768 + d * 384
                                       : gi + ((size_t)b * 100 + t0) * 768 + d * 384;
            gr[r] = g[j]; gz[r] = g[128 + j]; gn[r] = g[256 + j];
        }
    }
    lds_barrier();

    for (int ti = 0; ti < 100; ++ti) {
        int t = rev ? 99 - ti : ti;
        // prefetch gi(t+1): in flight across the whole step's compute
        float pr[4], pz[4], pn[4];
        if (!gi_tconst && ti < 99) {
            int tn2 = rev ? 99 - (ti + 1) : ti + 1;
            #pragma unroll
            for (int r = 0; r < 4; ++r) {
                int b = q * 16 + kq * 4 + r;
                const float* g = gi + ((size_t)b * 100 + tn2) * 768 + d * 384;
                pr[r] = g[j]; pz[r] = g[128 + j]; pn[r] = g[256 + j];
            }
        }
        // A-frags: A[m=lm][k] from current h buffer
        const ushort* hb = hbuf[ti & 1];
        bf16x8 afr[4];
        #pragma unroll
        for (int kb = 0; kb < 4; ++kb)
            afr[kb] = *reinterpret_cast<const bf16x8*>(&hb[lm * 136 + kb * 32 + kq * 8]);
        // gh = h @ Whh.T : three acc chains (r,z,n) land in this lane's registers
        f32x4 aR = {0,0,0,0}, aZ = {0,0,0,0}, aN = {0,0,0,0};
        #pragma unroll
        for (int kb = 0; kb < 4; ++kb) {
            aR = __builtin_amdgcn_mfma_f32_16x16x32_bf16(afr[kb], bfr[0][kb], aR, 0, 0, 0);
            aZ = __builtin_amdgcn_mfma_f32_16x16x32_bf16(afr[kb], bfr[1][kb], aZ, 0, 0, 0);
            aN = __builtin_amdgcn_mfma_f32_16x16x32_bf16(afr[kb], bfr[2][kb], aN, 0, 0, 0);
        }
        // nonlinearity, fully in-register (gi already has bih + bhh_{r,z} folded)
        ushort* hw = hbuf[(ti + 1) & 1];
        #pragma unroll
        for (int r = 0; r < 4; ++r) {
            float rr = sigm(gr[r] + aR[r]);
            float zz = sigm(gz[r] + aZ[r]);
            float nn = tanh_f(gn[r] + rr * (aN[r] + bhn));
            float h = nn + zz * (hreg[r] - nn);
            hreg[r] = h;
            hw[(kq * 4 + r) * 136 + j] = f2bf(h);
            if (y) {
                int b = q * 16 + kq * 4 + r;
                y[((size_t)b * 100 + t) * 256 + d * 128 + j] = f2bf(h);
            }
        }
        if (!gi_tconst && ti < 99) {
            #pragma unroll
            for (int r = 0; r < 4; ++r) { gr[r] = pr[r]; gz[r] = pz[r]; gn[r] = pn[r]; }
        }
        lds_barrier();   // LDS-only: y stores stay in flight; kernel-end drain covers them
    }
    #pragma unroll
    for (int r = 0; r < 4; ++r) {
        int b = q * 16 + kq * 4 + r;
        int col = hoff + d * 128 + j;   // torch hidden layout: [l0f,l0b,l1f,l1b]
        hf32[(size_t)b * 512 + col] = hreg[r];
        if (hbf) hbf[(size_t)b * 512 + col] = f2bf(hreg[r]);
    }
}

// ---------------------------------------------------------------- fc head: out = [enc_h, dec_h] @ fc_W.T + fc_b
__global__ __launch_bounds__(256) void fc_out(const float* __restrict__ ench,
                                              const float* __restrict__ dech,
                                              const float* __restrict__ W,
                                              const float* __restrict__ bias,
                                              float* __restrict__ out) {
    __shared__ float v[1024];
    int b = blockIdx.x, tid = threadIdx.x;
    for (int i = tid; i < 1024; i += 256)
        v[i] = (i < 512) ? ench[b * 512 + i] : dech[b * 512 + i - 512];
    __syncthreads();
    int wave = tid >> 6, lane = tid & 63;
    for (int c = wave; c < 20; c += 4) {
        float s = 0.f;
        for (int k = lane; k < 1024; k += 64) s += v[k] * W[c * 1024 + k];
        #pragma unroll
        for (int off = 32; off >= 1; off >>= 1) s += __shfl_xor(s, off, 64);
        if (lane == 0) out[b * 20 + c] = s + bias[c];
    }
}

// ---------------------------------------------------------------- launch
extern "C" void kernel_launch(void* const* d_in, const int* in_sizes, int n_in,
                              void* d_out, int out_size, void* d_ws, size_t ws_size,
                              hipStream_t stream) {
    const int*   x     = (const int*)  d_in[0];
    const float* emb   = (const float*)d_in[1];
    const float* eWih0 = (const float*)d_in[2];
    const float* eWhh0 = (const float*)d_in[3];
    const float* ebih0 = (const float*)d_in[4];
    const float* ebhh0 = (const float*)d_in[5];
    const float* eWih1 = (const float*)d_in[6];
    const float* eWhh1 = (const float*)d_in[7];
    const float* ebih1 = (const float*)d_in[8];
    const float* ebhh1 = (const float*)d_in[9];
    const float* dWih0 = (const float*)d_in[10];
    const float* dWhh0 = (const float*)d_in[11];
    const float* dbih0 = (const float*)d_in[12];
    const float* dbhh0 = (const float*)d_in[13];
    const float* dWih1 = (const float*)d_in[14];
    const float* dWhh1 = (const float*)d_in[15];
    const float* dbih1 = (const float*)d_in[16];
    const float* dbhh1 = (const float*)d_in[17];
    const float* fcW   = (const float*)d_in[18];
    const float* fcb   = (const float*)d_in[19];
    const float* recW  = (const float*)d_in[20];
    const float* recb  = (const float*)d_in[21];

    char* ws = (char*)d_ws;
    size_t off = 0;
    auto alloc = [&](size_t bytes) {
        char* p = ws + off;
        off = (off + bytes + 255) & ~(size_t)255;
        return p;
    };
    float*  gi    = (float*) alloc((size_t)6400 * 768 * 4);   // gate inputs (fp32, reused 3x)
    ushort* yA    = (ushort*)alloc((size_t)6400 * 256 * 2);   // enc l0 / dec l0 output seq (bf16)
    ushort* y1d   = (ushort*)alloc((size_t)6400 * 256 * 2);   // dec l1 output = rec_seq (bf16)
    ushort* wbuf  = (ushort*)alloc((size_t)3444736 * 2);      // bf16: eWih0|eWih1|dWih0|dWih1|recW
    float*  digi  = (float*) alloc((size_t)64 * 768 * 4);     // dec l0 time-constant gi
    float*  enchf = (float*) alloc((size_t)64 * 512 * 4);
    ushort* enchb = (ushort*)alloc((size_t)64 * 512 * 2);
    float*  dechf = (float*) alloc((size_t)64 * 512 * 4);
    alloc(65536);   // tail slack: OOB tile reads (N/M tails) stay inside ws
    (void)ws_size;

    ushort* w_e0  = wbuf;
    ushort* w_e1  = wbuf + 98304;
    ushort* w_d0  = wbuf + 294912;
    ushort* w_d1  = wbuf + 688128;
    ushort* w_rec = wbuf + 884736;

    float* out_fc  = (float*)d_out;              // [64][20]
    float* out_rec = (float*)d_out + 1280;       // [64][100][10000]

    // one-shot weight conversion (all Wih + recW -> bf16), 430592 threads exactly
    cvt_all<<<1682, 256, 0, stream>>>(eWih0, eWih1, dWih0, dWih1, recW, wbuf);

    // encoder layer 0: A gathered from emb via x (bhh r,z folded into gi)
    gemm_bt<true, false><<<dim3(6, 50), 256, 0, stream>>>(nullptr, 128, w_e0, 128, ebih0, ebhh0,
                                                          gi, 768, 6400, 768, 128, emb, x);
    gru_scan<<<8, 512, 0, stream>>>(gi, 0, eWhh0, ebhh0, yA, enchf, enchb, 0);
    // encoder layer 1 (only final h needed)
    gemm_bt<false, false><<<dim3(6, 50), 256, 0, stream>>>(yA, 256, w_e1, 256, ebih1, ebhh1,
                                                           gi, 768, 6400, 768, 256, nullptr, nullptr);
    gru_scan<<<8, 512, 0, stream>>>(gi, 0, eWhh1, ebhh1, nullptr, enchf, enchb, 256);
    // decoder layer 0: broadcast enc_h -> gi constant over t
    gemm_bt<false, false><<<dim3(6, 1), 256, 0, stream>>>(enchb, 512, w_d0, 512, dbih0, dbhh0,
                                                          digi, 768, 64, 768, 512, nullptr, nullptr);
    gru_scan<<<8, 512, 0, stream>>>(digi, 1, dWhh0, dbhh0, yA, dechf, nullptr, 0);
    // decoder layer 1
    gemm_bt<false, false><<<dim3(6, 50), 256, 0, stream>>>(yA, 256, w_d1, 256, dbih1, dbhh1,
                                                           gi, 768, 6400, 768, 256, nullptr, nullptr);
    gru_scan<<<8, 512, 0, stream>>>(gi, 0, dWhh1, dbhh1, y1d, dechf, nullptr, 256);
    // reconstruction GEMM (nontemporal C: 256MB write bypasses cache pollution)
    gemm_bt<false, true><<<dim3(79, 50), 256, 0, stream>>>(y1d, 256, w_rec, 256, recb, nullptr,
                                                           out_rec, 10000, 6400, 10000, 256, nullptr, nullptr);
    // fc head
    fc_out<<<64, 256, 0, stream>>>(enchf, dechf, fcW, fcb, out_fc);
}